// Round 13
// baseline (558.536 us; speedup 1.0000x reference)
//
#include <hip/hip_runtime.h>
#include <hip/hip_bf16.h>

typedef unsigned short u16;
typedef short s8v __attribute__((ext_vector_type(8)));
typedef float f16v __attribute__((ext_vector_type(16)));
typedef float f4v  __attribute__((ext_vector_type(4)));

#define N_IMG   2048
#define F       64
#define EXPERTS 4
#define NBLK    4
#define CAP     768
#define CLS_CH  16
#define OUT_PER_IMG (3*64*64)

// LDS layout (k_sr)
#define ACT_BYTES (1156*64*2)          // 147968: [pix 34*34][64ch] bf16, swizzled
#define IMG_OFF   ACT_BYTES
#define IMG_BYTES (1156*4*2)           // 9248: [pix][4ch] bf16 (ch3 = 0)
#define LDS_BYTES (ACT_BYTES + IMG_BYTES)   // 157216 <= 160 KiB

// act swizzle: pixel p (0..1155), channel-byte c (0..127), 16B-slot XOR
#define SWZB(p, c) (((p) << 7) + ((c) ^ (((p) & 7) << 4)))

// ws layout (bytes)
// weights stored wave-contiguous: one load instr = 64 lanes x 16B = 1KB chunk
#define WS_EXPERT   0
#define WS_PERM     8192
#define WS_VLD      16384
#define WS_BODY     24576                        // [lb][tap][kc][ot][lane][8]  16*36864 elems
#define WS_HEAD     (WS_BODY + 589824*2)         // [e][kc3][ot][lane][8]       4*3072 elems
#define WS_TAIL     (WS_HEAD + 12288*2)          // [e][kstep18][lane][8]       4*9216 elems (16x16 frag)

__device__ __forceinline__ u16 f2bf(float v) {
    return __builtin_bit_cast(u16, __float2bfloat16(v));
}
__device__ __forceinline__ unsigned pk2(float a, float b) {
    return (unsigned)f2bf(a) | ((unsigned)f2bf(b) << 16);
}

// ---------------- weight prep: fp32 -> bf16, wave-contiguous MFMA layouts -----
__global__ __launch_bounds__(256) void k_prep(
    const float* __restrict__ hw, const float* __restrict__ bw,
    const float* __restrict__ tw, u16* __restrict__ oh,
    u16* __restrict__ ob, u16* __restrict__ otl)
{
    const int i = blockIdx.x * 256 + threadIdx.x;
    if (i < 589824) {                       // body (32x32 A-frag)
        const int j = i & 7, lane = (i >> 3) & 63, ot = (i >> 9) & 1;
        const int kc = (i >> 10) & 3, tap = (i >> 12) % 9, lb = i / 36864;
        const int oc = ot*32 + (lane & 31);
        const int ci = kc*16 + (lane >> 5)*8 + j;
        ob[i] = f2bf(bw[((lb*64 + oc)*64 + ci)*9 + tap]);
    } else if (i < 589824 + 12288) {        // head: k = tap*4+ci, zero-padded to 48
        const int i2 = i - 589824;
        const int j = i2 & 7, lane = (i2 >> 3) & 63, ot = (i2 >> 9) & 1;
        const int kc = (i2 >> 10) % 3, e = i2 / 3072;
        const int oc = ot*32 + (lane & 31);
        const int k = kc*16 + (lane >> 5)*8 + j;
        const int tap = k >> 2, ci = k & 3;
        const float v = (k < 36 && ci < 3) ? hw[((e*64 + oc)*3 + ci)*9 + tap] : 0.f;
        oh[i2] = f2bf(v);
    } else if (i < 589824 + 12288 + 36864) {  // tail: 16x16 A-frag, 12 oc padded to 16
        const int i2 = i - 602112;
        const int j = i2 & 7, lane = (i2 >> 3) & 63;
        const int ks = (i2 >> 9) % 18, e = i2 / 9216;
        const int oc = lane & 15;                    // A row = lane&15
        const int kl = (lane >> 4)*8 + j;            // k local (0..31)
        const int tap = ks >> 1, ci = (ks & 1)*32 + kl;
        const float v = (oc < 12) ? tw[((e*12 + oc)*64 + ci)*9 + tap] : 0.f;
        otl[i2] = f2bf(v);
    }
}

// ---------------- classifier ---------------------------------------------------
__global__ __launch_bounds__(256) void k_classify(
    const float* __restrict__ inp, const float* __restrict__ w1,
    const float* __restrict__ b1, const float* __restrict__ wfc,
    const float* __restrict__ bfc, int* __restrict__ expert)
{
    __shared__ float img[3*1024];
    __shared__ float wred[4][CLS_CH];
    __shared__ float meanf[CLS_CH];
    const int n = blockIdx.x, t = threadIdx.x;
    const float* src = inp + (size_t)n*3072;
    {
        const float4* s4 = (const float4*)src;
        float4* d4 = (float4*)img;
        for (int i = t; i < 768; i += 256) d4[i] = s4[i];
    }
    __syncthreads();

    float sums[CLS_CH];
    #pragma unroll
    for (int c = 0; c < CLS_CH; ++c) sums[c] = 0.f;

    #pragma unroll
    for (int k4 = 0; k4 < 4; ++k4) {
        const int p = t + k4*256, y = p >> 5, x = p & 31;
        float v[27];
        #pragma unroll
        for (int ci = 0; ci < 3; ++ci)
            #pragma unroll
            for (int dy = 0; dy < 3; ++dy)
                #pragma unroll
                for (int dx = 0; dx < 3; ++dx) {
                    const int py = y + dy - 1, px = x + dx - 1;
                    v[ci*9 + dy*3 + dx] =
                        ((unsigned)py < 32u && (unsigned)px < 32u)
                            ? img[ci*1024 + py*32 + px] : 0.f;
                }
        for (int c = 0; c < CLS_CH; ++c) {
            float o = b1[c];
            #pragma unroll
            for (int k = 0; k < 27; ++k) o += w1[c*27 + k] * v[k];
            sums[c] += fmaxf(o, 0.f);
        }
    }

    #pragma unroll
    for (int c = 0; c < CLS_CH; ++c) {
        float s = sums[c];
        #pragma unroll
        for (int m = 32; m >= 1; m >>= 1) s += __shfl_xor(s, m);
        sums[c] = s;
    }
    const int lane = t & 63, wv = t >> 6;
    if (lane == 0)
        #pragma unroll
        for (int c = 0; c < CLS_CH; ++c) wred[wv][c] = sums[c];
    __syncthreads();
    if (t < CLS_CH)
        meanf[t] = (wred[0][t] + wred[1][t] + wred[2][t] + wred[3][t]) * (1.0f/1024.0f);
    __syncthreads();
    if (t == 0) {
        float best = -1e30f; int bi = 0;
        for (int e = 0; e < EXPERTS; ++e) {
            float sc = bfc[e];
            for (int cc = 0; cc < CLS_CH; ++cc) sc += wfc[e*CLS_CH + cc] * meanf[cc];
            if (sc > best) { best = sc; bi = e; }   // strict >: first-max == jnp.argmax
        }
        expert[n] = bi;
    }
}

// ---------------- routing: expert-sorted permutation (wave ballot-scan) -------
__global__ __launch_bounds__(256) void k_route(
    const int* __restrict__ expert, int* __restrict__ perm, int* __restrict__ vld)
{
    __shared__ int cnt[EXPERTS];
    __shared__ int vbase[EXPERTS], obase[EXPERTS];
    const int t = threadIdx.x;
    const int wv = t >> 6, lane = t & 63;

    int my = 0;
    for (int c = 0; c < N_IMG/64; ++c) {
        const int e = expert[c*64 + lane];
        const unsigned long long m = __ballot(e == wv);
        my += (int)__popcll(m);
    }
    if (lane == 0) cnt[wv] = my;
    __syncthreads();
    if (t == 0) {
        int vb = 0;
        for (int e = 0; e < EXPERTS; ++e) {
            vbase[e] = vb; vb += (cnt[e] < CAP ? cnt[e] : CAP);
        }
        int ob = vb;
        for (int e = 0; e < EXPERTS; ++e) {
            obase[e] = ob; ob += (cnt[e] > CAP ? cnt[e] - CAP : 0);
        }
    }
    __syncthreads();

    int base = 0;
    for (int c = 0; c < N_IMG/64; ++c) {
        const int n = c*64 + lane;
        const int e = expert[n];
        const unsigned long long m = __ballot(e == wv);
        if (e == wv) {
            const int rank = base + (int)__popcll(m & ((1ull << lane) - 1ull));
            int slot, v;
            if (rank < CAP) { slot = vbase[wv] + rank;       v = 1; }
            else            { slot = obase[wv] + rank - CAP; v = 0; }
            perm[slot] = n; vld[slot] = v;
        }
        base += (int)__popcll(m);
    }
}

// ---------------- MFMA building blocks --------------------------------------
__device__ __forceinline__ s8v ld_act(const char* actb, int p, int c) {
    return *reinterpret_cast<const s8v*>(actb + SWZB(p, c));
}
__device__ __forceinline__ s8v ld_w(const u16* w, int eoff) {
    return *reinterpret_cast<const s8v*>(w + eoff);
}

// acc[4 row-tiles], wave owns 32 oc (its ot half). bp pre-offset by ot*32.
__device__ __forceinline__ void bias_init(f16v acc[4], const float* bp, int h) {
    #pragma unroll
    for (int g = 0; g < 4; ++g) {
        const float4 bv = *reinterpret_cast<const float4*>(bp + g*8 + h*4);
        const float* b4 = (const float*)&bv;
        #pragma unroll
        for (int pt = 0; pt < 4; ++pt)
            #pragma unroll
            for (int i = 0; i < 4; ++i)
                acc[pt][g*4+i] = b4[i];
    }
}
__device__ __forceinline__ void bias_add(f16v acc[4], const float* bp, int h) {
    #pragma unroll
    for (int g = 0; g < 4; ++g) {
        const float4 bv = *reinterpret_cast<const float4*>(bp + g*8 + h*4);
        const float* b4 = (const float*)&bv;
        #pragma unroll
        for (int pt = 0; pt < 4; ++pt)
            #pragma unroll
            for (int i = 0; i < 4; ++i)
                acc[pt][g*4+i] += b4[i];
    }
}

// body conv GEMM, wave = 4 rows x 32 oc: kc -> dx -> {6 row loads} -> dy {1 w load + 4 MFMA}
// setprio(1) around each dy's MFMA quad (T5): mid-layer, waves are at different
// (kc,dx) groups, so the scheduler can favor MFMA-ready waves.
__device__ __forceinline__ void body_gemm(f16v acc[4], const char* actb,
                                          const u16* wb, int lane, int ot, int y0) {
    const int r31 = lane & 31, h = lane >> 5;
    #pragma unroll
    for (int kc = 0; kc < 4; ++kc) {
        const int coff = kc*32 + h*16;
        #pragma unroll
        for (int dx = 0; dx < 3; ++dx) {
            s8v ar[6];
            #pragma unroll
            for (int r = 0; r < 6; ++r)
                ar[r] = ld_act(actb, (y0 + r)*34 + r31 + dx, coff);
            #pragma unroll
            for (int dy = 0; dy < 3; ++dy) {
                const s8v w0 = ld_w(wb, ((dy*3 + dx)*4 + kc)*1024 + ot*512 + lane*8);
                __builtin_amdgcn_s_setprio(1);
                #pragma unroll
                for (int pt = 0; pt < 4; ++pt)
                    acc[pt] = __builtin_amdgcn_mfma_f32_32x32x16_bf16(w0, ar[dy+pt], acc[pt], 0,0,0);
                __builtin_amdgcn_s_setprio(0);
            }
        }
    }
}

// head conv GEMM (3ch image, K = tap*4+ci zero-padded to 48), wave's ot half
__device__ __forceinline__ void head_gemm(f16v acc[4], const char* imgb,
                                          const u16* hw, int lane, int ot, int y0) {
    const int r31 = lane & 31, h = lane >> 5;
    #pragma unroll
    for (int kc = 0; kc < 3; ++kc) {
        const s8v w0 = ld_w(hw, kc*1024 + ot*512 + lane*8);
        #pragma unroll
        for (int pt = 0; pt < 4; ++pt) {
            const int y = y0 + pt;
            const int tA = kc*4 + h*2, tB = tA + 1;
            const int pA = (tA <= 8) ? (y + tA/3)*34 + r31 + (tA % 3) : 0;
            const int pB = (tB <= 8) ? (y + tB/3)*34 + r31 + (tB % 3) : 0;
            const uint2 lo = *reinterpret_cast<const uint2*>(imgb + pA*8);
            const uint2 hi = *reinterpret_cast<const uint2*>(imgb + pB*8);
            uint4 tmp; tmp.x = lo.x; tmp.y = lo.y; tmp.z = hi.x; tmp.w = hi.y;
            const s8v bf = __builtin_bit_cast(s8v, tmp);
            acc[pt] = __builtin_amdgcn_mfma_f32_32x32x16_bf16(w0, bf, acc[pt], 0,0,0);
        }
    }
}

// write acc (32 oc half) -> act LDS. C/D: oc_in_32 = i + 8*g + 4*h, col = r31
__device__ __forceinline__ void st_act(char* actb, const f16v acc[4],
                                       int r31, int h, int ot, int y0) {
    #pragma unroll
    for (int pt = 0; pt < 4; ++pt) {
        const int p = (y0 + pt + 1)*34 + r31 + 1;
        #pragma unroll
        for (int g = 0; g < 4; ++g) {
            uint2 wv;
            wv.x = pk2(acc[pt][g*4+0], acc[pt][g*4+1]);
            wv.y = pk2(acc[pt][g*4+2], acc[pt][g*4+3]);
            *reinterpret_cast<uint2*>(actb + SWZB(p, ot*64 + g*16 + h*8)) = wv;
        }
    }
}

// ---------------- SR trunk (MFMA) --------------------------------------------
// 16 waves; wave wv: rows (wv>>1)*4.., oc half (wv&1)*32. One image per block.
__global__ __launch_bounds__(1024, 4) void k_sr(
    const float* __restrict__ inp,
    const float* __restrict__ head_b, const float* __restrict__ body_b,
    const float* __restrict__ tail_b,
    const u16* __restrict__ bw_head, const u16* __restrict__ bw_body,
    const u16* __restrict__ bw_tail,
    const int* __restrict__ perm, const int* __restrict__ vld,
    const int* __restrict__ expert, float* __restrict__ out)
{
    extern __shared__ char lds[];
    char* actb = lds;
    char* imgb = lds + IMG_OFF;
    const int slot = blockIdx.x, t = threadIdx.x;
    const int n = perm[slot];
    float* outp = out + (size_t)n * OUT_PER_IMG;

    if (!vld[slot]) {                      // over-capacity: zeros
        float4 z; z.x = z.y = z.z = z.w = 0.f;
        float4* o4 = (float4*)outp;
        #pragma unroll
        for (int k = 0; k < 3; ++k) o4[k*1024 + t] = z;
        return;
    }
    const int e = expert[n];

    // zero only act pad pixels (rows 0/33, cols 0/33) + whole img area;
    // act interior is fully overwritten by head's st_act before any read.
    for (int i = t; i < 132*32; i += 1024) {
        const int pp = i >> 5, d = i & 31;
        int p;
        if (pp < 34)       p = pp;                    // row 0
        else if (pp < 68)  p = 33*34 + (pp - 34);     // row 33
        else if (pp < 100) p = (pp - 68 + 1)*34;      // col 0, rows 1..32
        else               p = (pp - 100 + 1)*34 + 33;// col 33, rows 1..32
        ((unsigned*)(actb + ((size_t)p << 7)))[d] = 0u;
    }
    for (int i = t; i < IMG_BYTES/4; i += 1024) ((unsigned*)imgb)[i] = 0u;
    __syncthreads();

    const float* src = inp + (size_t)n*3072;
    #pragma unroll
    for (int k = 0; k < 3; ++k) {
        const int i = t + k*1024;
        const int ci = i >> 10, p = i & 1023, y = p >> 5, x = p & 31;
        ((u16*)imgb)[((y+1)*34 + x + 1)*4 + ci] = f2bf(src[i]);
    }
    __syncthreads();

    const int lane = t & 63, wv = t >> 6;
    const int r31 = lane & 31, h = lane >> 5;
    const int ot = wv & 1;                 // oc half
    const int y0 = (wv >> 1) * 4;          // wave's 4 output rows

    const u16* hw = bw_head + e*3072;
    const float* hb = head_b + e*64 + ot*32;

    f16v acc[4];

    // ---- head
    bias_init(acc, hb, h);
    head_gemm(acc, imgb, hw, lane, ot, y0);
    st_act(actb, acc, r31, h, ot, y0);
    __syncthreads();

    // ---- body blocks
    for (int b = 0; b < NBLK; ++b) {
        const u16* wb = bw_body + (size_t)(e*NBLK + b)*36864;
        bias_init(acc, body_b + (e*NBLK + b)*64 + ot*32, h);
        body_gemm(acc, actb, wb, lane, ot, y0);
        #pragma unroll
        for (int pt = 0; pt < 4; ++pt)
            #pragma unroll
            for (int i = 0; i < 16; ++i)
                acc[pt][i] = fmaxf(acc[pt][i], 0.f);
        if (b == NBLK-1) {                  // + h0 recomputed from staged image
            bias_add(acc, hb, h);
            head_gemm(acc, imgb, hw, lane, ot, y0);
        }
        __syncthreads();
        st_act(actb, acc, r31, h, ot, y0);
        __syncthreads();
    }

    // ---- tail: conv 64->12 via 16x16x32 MFMA (oc padded 12->16) + pixel shuffle
    // wave = 2 rows x 32 px = 4 tiles of 16 px. A row=lane&15 (oc), k=(lane>>4)*8+j.
    {
        const u16* tw = bw_tail + e*9216;
        const float* tb = tail_b + e*12;
        const int y0t = wv * 2;
        const int g16 = lane >> 4;          // 0..3: oc group (A k-half selector too)
        const int p16 = lane & 15;
        f4v tacc[4];
        #pragma unroll
        for (int tl = 0; tl < 4; ++tl)
            #pragma unroll
            for (int i = 0; i < 4; ++i) {
                const int oc = g16*4 + i;
                tacc[tl][i] = (oc < 12) ? tb[oc] : 0.f;
            }
        #pragma unroll
        for (int ks = 0; ks < 18; ++ks) {
            const int tap = ks >> 1, half = ks & 1;
            const int dy = tap / 3, dx = tap % 3;
            const s8v twf = ld_w(tw, ks*512 + lane*8);
            const int cb = half*64 + g16*16;     // ci = half*32 + g16*8 (+j), bytes x2
            __builtin_amdgcn_s_setprio(1);
            #pragma unroll
            for (int tl = 0; tl < 4; ++tl) {
                const int row = y0t + (tl >> 1);
                const int p = (row + dy)*34 + (tl & 1)*16 + p16 + dx;
                const s8v bfr = ld_act(actb, p, cb);
                tacc[tl] = __builtin_amdgcn_mfma_f32_16x16x32_bf16(twf, bfr, tacc[tl], 0,0,0);
            }
            __builtin_amdgcn_s_setprio(0);
        }
        // store: C col=lane&15=px, row=(lane>>4)*4+reg=oc. oc<12 <=> g16<3.
        if (g16 < 3) {
            #pragma unroll
            for (int tl = 0; tl < 4; ++tl) {
                const int ys = y0t + (tl >> 1);
                const int xo = 2*((tl & 1)*16 + p16);
                float2 v01, v23;
                v01.x = tacc[tl][0]; v01.y = tacc[tl][1];
                v23.x = tacc[tl][2]; v23.y = tacc[tl][3];
                *reinterpret_cast<float2*>(&outp[g16*4096 + (2*ys)*64 + xo])     = v01;
                *reinterpret_cast<float2*>(&outp[g16*4096 + (2*ys + 1)*64 + xo]) = v23;
            }
        }
    }
}

extern "C" void kernel_launch(void* const* d_in, const int* in_sizes, int n_in,
                              void* d_out, int out_size, void* d_ws, size_t ws_size,
                              hipStream_t stream) {
    const float* inp     = (const float*)d_in[0];
    const float* cls_w1  = (const float*)d_in[1];
    const float* cls_b1  = (const float*)d_in[2];
    const float* cls_wfc = (const float*)d_in[3];
    const float* cls_bfc = (const float*)d_in[4];
    const float* head_w  = (const float*)d_in[5];
    const float* head_b  = (const float*)d_in[6];
    const float* body_w  = (const float*)d_in[7];
    const float* body_b  = (const float*)d_in[8];
    const float* tail_w  = (const float*)d_in[9];
    const float* tail_b  = (const float*)d_in[10];
    float* out = (float*)d_out;

    char* ws = (char*)d_ws;
    int* expert = (int*)(ws + WS_EXPERT);
    int* perm   = (int*)(ws + WS_PERM);
    int* vld    = (int*)(ws + WS_VLD);
    u16* bw_body = (u16*)(ws + WS_BODY);
    u16* bw_head = (u16*)(ws + WS_HEAD);
    u16* bw_tail = (u16*)(ws + WS_TAIL);

    hipFuncSetAttribute((const void*)k_sr,
                        hipFuncAttributeMaxDynamicSharedMemorySize, LDS_BYTES);

    k_prep<<<(638976 + 255)/256, 256, 0, stream>>>(head_w, body_w, tail_w,
                                                   bw_head, bw_body, bw_tail);
    k_classify<<<N_IMG, 256, 0, stream>>>(inp, cls_w1, cls_b1, cls_wfc, cls_bfc, expert);
    k_route<<<1, 256, 0, stream>>>(expert, perm, vld);
    k_sr<<<N_IMG, 1024, LDS_BYTES, stream>>>(inp, head_b, body_b, tail_b,
                                             bw_head, bw_body, bw_tail,
                                             perm, vld, expert, out);
}

// Round 14
// 490.222 us; speedup vs baseline: 1.1394x; 1.1394x over previous
//
#include <hip/hip_runtime.h>
#include <hip/hip_bf16.h>

typedef unsigned short u16;
typedef short s8v __attribute__((ext_vector_type(8)));
typedef float f16v __attribute__((ext_vector_type(16)));
typedef float f4v  __attribute__((ext_vector_type(4)));

#define N_IMG   2048
#define F       64
#define EXPERTS 4
#define NBLK    4
#define CAP     768
#define CLS_CH  16
#define OUT_PER_IMG (3*64*64)

// LDS layout (k_sr)
#define ACT_BYTES (1156*64*2)          // 147968: [pix 34*34][64ch] bf16, swizzled
#define IMG_OFF   ACT_BYTES
#define IMG_BYTES (1156*4*2)           // 9248: [pix][4ch] bf16 (ch3 = 0)
#define LDS_BYTES (ACT_BYTES + IMG_BYTES)   // 157216 <= 160 KiB

// act swizzle: pixel p (0..1155), channel-byte c (0..127), 16B-slot XOR
#define SWZB(p, c) (((p) << 7) + ((c) ^ (((p) & 7) << 4)))

// ws layout (bytes)
// weights stored wave-contiguous: one load instr = 64 lanes x 16B = 1KB chunk
#define WS_EXPERT   0
#define WS_PERM     8192
#define WS_VLD      16384
#define WS_BODY     24576                        // [lb][tap][kc][ot][lane][8]  16*36864 elems
#define WS_HEAD     (WS_BODY + 589824*2)         // [e][kc3][ot][lane][8]       4*3072 elems
#define WS_TAIL     (WS_HEAD + 12288*2)          // [e][kstep18][lane][8]       4*9216 elems (16x16 frag)

__device__ __forceinline__ u16 f2bf(float v) {
    return __builtin_bit_cast(u16, __float2bfloat16(v));
}
__device__ __forceinline__ unsigned pk2(float a, float b) {
    return (unsigned)f2bf(a) | ((unsigned)f2bf(b) << 16);
}

// ---------------- weight prep: fp32 -> bf16, wave-contiguous MFMA layouts -----
__global__ __launch_bounds__(256) void k_prep(
    const float* __restrict__ hw, const float* __restrict__ bw,
    const float* __restrict__ tw, u16* __restrict__ oh,
    u16* __restrict__ ob, u16* __restrict__ otl)
{
    const int i = blockIdx.x * 256 + threadIdx.x;
    if (i < 589824) {                       // body (32x32 A-frag)
        const int j = i & 7, lane = (i >> 3) & 63, ot = (i >> 9) & 1;
        const int kc = (i >> 10) & 3, tap = (i >> 12) % 9, lb = i / 36864;
        const int oc = ot*32 + (lane & 31);
        const int ci = kc*16 + (lane >> 5)*8 + j;
        ob[i] = f2bf(bw[((lb*64 + oc)*64 + ci)*9 + tap]);
    } else if (i < 589824 + 12288) {        // head: k = tap*4+ci, zero-padded to 48
        const int i2 = i - 589824;
        const int j = i2 & 7, lane = (i2 >> 3) & 63, ot = (i2 >> 9) & 1;
        const int kc = (i2 >> 10) % 3, e = i2 / 3072;
        const int oc = ot*32 + (lane & 31);
        const int k = kc*16 + (lane >> 5)*8 + j;
        const int tap = k >> 2, ci = k & 3;
        const float v = (k < 36 && ci < 3) ? hw[((e*64 + oc)*3 + ci)*9 + tap] : 0.f;
        oh[i2] = f2bf(v);
    } else if (i < 589824 + 12288 + 36864) {  // tail: 16x16 A-frag, 12 oc padded to 16
        const int i2 = i - 602112;
        const int j = i2 & 7, lane = (i2 >> 3) & 63;
        const int ks = (i2 >> 9) % 18, e = i2 / 9216;
        const int oc = lane & 15;                    // A row = lane&15
        const int kl = (lane >> 4)*8 + j;            // k local (0..31)
        const int tap = ks >> 1, ci = (ks & 1)*32 + kl;
        const float v = (oc < 12) ? tw[((e*12 + oc)*64 + ci)*9 + tap] : 0.f;
        otl[i2] = f2bf(v);
    }
}

// ---------------- classifier ---------------------------------------------------
__global__ __launch_bounds__(256) void k_classify(
    const float* __restrict__ inp, const float* __restrict__ w1,
    const float* __restrict__ b1, const float* __restrict__ wfc,
    const float* __restrict__ bfc, int* __restrict__ expert)
{
    __shared__ float img[3*1024];
    __shared__ float wred[4][CLS_CH];
    __shared__ float meanf[CLS_CH];
    const int n = blockIdx.x, t = threadIdx.x;
    const float* src = inp + (size_t)n*3072;
    {
        const float4* s4 = (const float4*)src;
        float4* d4 = (float4*)img;
        for (int i = t; i < 768; i += 256) d4[i] = s4[i];
    }
    __syncthreads();

    float sums[CLS_CH];
    #pragma unroll
    for (int c = 0; c < CLS_CH; ++c) sums[c] = 0.f;

    #pragma unroll
    for (int k4 = 0; k4 < 4; ++k4) {
        const int p = t + k4*256, y = p >> 5, x = p & 31;
        float v[27];
        #pragma unroll
        for (int ci = 0; ci < 3; ++ci)
            #pragma unroll
            for (int dy = 0; dy < 3; ++dy)
                #pragma unroll
                for (int dx = 0; dx < 3; ++dx) {
                    const int py = y + dy - 1, px = x + dx - 1;
                    v[ci*9 + dy*3 + dx] =
                        ((unsigned)py < 32u && (unsigned)px < 32u)
                            ? img[ci*1024 + py*32 + px] : 0.f;
                }
        for (int c = 0; c < CLS_CH; ++c) {
            float o = b1[c];
            #pragma unroll
            for (int k = 0; k < 27; ++k) o += w1[c*27 + k] * v[k];
            sums[c] += fmaxf(o, 0.f);
        }
    }

    #pragma unroll
    for (int c = 0; c < CLS_CH; ++c) {
        float s = sums[c];
        #pragma unroll
        for (int m = 32; m >= 1; m >>= 1) s += __shfl_xor(s, m);
        sums[c] = s;
    }
    const int lane = t & 63, wv = t >> 6;
    if (lane == 0)
        #pragma unroll
        for (int c = 0; c < CLS_CH; ++c) wred[wv][c] = sums[c];
    __syncthreads();
    if (t < CLS_CH)
        meanf[t] = (wred[0][t] + wred[1][t] + wred[2][t] + wred[3][t]) * (1.0f/1024.0f);
    __syncthreads();
    if (t == 0) {
        float best = -1e30f; int bi = 0;
        for (int e = 0; e < EXPERTS; ++e) {
            float sc = bfc[e];
            for (int cc = 0; cc < CLS_CH; ++cc) sc += wfc[e*CLS_CH + cc] * meanf[cc];
            if (sc > best) { best = sc; bi = e; }   // strict >: first-max == jnp.argmax
        }
        expert[n] = bi;
    }
}

// ---------------- routing: expert-sorted permutation (LDS-staged ballot-scan) --
__global__ __launch_bounds__(256) void k_route(
    const int* __restrict__ expert, int* __restrict__ perm, int* __restrict__ vld)
{
    __shared__ int se[N_IMG];              // 8 KB: stage once, coalesced
    __shared__ int cnt[EXPERTS];
    __shared__ int vbase[EXPERTS], obase[EXPERTS];
    const int t = threadIdx.x;
    const int wv = t >> 6, lane = t & 63;  // wave wv handles expert wv

    for (int i = t; i < N_IMG; i += 256) se[i] = expert[i];
    __syncthreads();

    // pass 1: per-expert totals (reads from LDS, ~120cyc not ~900)
    int my = 0;
    for (int c = 0; c < N_IMG/64; ++c) {
        const int e = se[c*64 + lane];
        my += (int)__popcll(__ballot(e == wv));
    }
    if (lane == 0) cnt[wv] = my;
    __syncthreads();
    if (t == 0) {
        int vb = 0;
        for (int e = 0; e < EXPERTS; ++e) {
            vbase[e] = vb; vb += (cnt[e] < CAP ? cnt[e] : CAP);
        }
        int ob = vb;
        for (int e = 0; e < EXPERTS; ++e) {
            obase[e] = ob; ob += (cnt[e] > CAP ? cnt[e] - CAP : 0);
        }
    }
    __syncthreads();

    // pass 2: slot assignment
    int base = 0;
    for (int c = 0; c < N_IMG/64; ++c) {
        const int n = c*64 + lane;
        const int e = se[n];
        const unsigned long long m = __ballot(e == wv);
        if (e == wv) {
            const int rank = base + (int)__popcll(m & ((1ull << lane) - 1ull));
            int slot, v;
            if (rank < CAP) { slot = vbase[wv] + rank;       v = 1; }
            else            { slot = obase[wv] + rank - CAP; v = 0; }
            perm[slot] = n; vld[slot] = v;
        }
        base += (int)__popcll(m);
    }
}

// ---------------- MFMA building blocks --------------------------------------
__device__ __forceinline__ s8v ld_act(const char* actb, int p, int c) {
    return *reinterpret_cast<const s8v*>(actb + SWZB(p, c));
}
__device__ __forceinline__ s8v ld_w(const u16* w, int eoff) {
    return *reinterpret_cast<const s8v*>(w + eoff);
}

// acc[4 row-tiles], wave owns 32 oc (its ot half). bp pre-offset by ot*32.
__device__ __forceinline__ void bias_init(f16v acc[4], const float* bp, int h) {
    #pragma unroll
    for (int g = 0; g < 4; ++g) {
        const float4 bv = *reinterpret_cast<const float4*>(bp + g*8 + h*4);
        const float* b4 = (const float*)&bv;
        #pragma unroll
        for (int pt = 0; pt < 4; ++pt)
            #pragma unroll
            for (int i = 0; i < 4; ++i)
                acc[pt][g*4+i] = b4[i];
    }
}
__device__ __forceinline__ void bias_add(f16v acc[4], const float* bp, int h) {
    #pragma unroll
    for (int g = 0; g < 4; ++g) {
        const float4 bv = *reinterpret_cast<const float4*>(bp + g*8 + h*4);
        const float* b4 = (const float*)&bv;
        #pragma unroll
        for (int pt = 0; pt < 4; ++pt)
            #pragma unroll
            for (int i = 0; i < 4; ++i)
                acc[pt][g*4+i] += b4[i];
    }
}

// body conv GEMM, wave = 4 rows x 32 oc: kc -> dx -> {6 row loads} -> dy {1 w load + 4 MFMA}
__device__ __forceinline__ void body_gemm(f16v acc[4], const char* actb,
                                          const u16* wb, int lane, int ot, int y0) {
    const int r31 = lane & 31, h = lane >> 5;
    #pragma unroll
    for (int kc = 0; kc < 4; ++kc) {
        const int coff = kc*32 + h*16;
        #pragma unroll
        for (int dx = 0; dx < 3; ++dx) {
            s8v ar[6];
            #pragma unroll
            for (int r = 0; r < 6; ++r)
                ar[r] = ld_act(actb, (y0 + r)*34 + r31 + dx, coff);
            #pragma unroll
            for (int dy = 0; dy < 3; ++dy) {
                const s8v w0 = ld_w(wb, ((dy*3 + dx)*4 + kc)*1024 + ot*512 + lane*8);
                #pragma unroll
                for (int pt = 0; pt < 4; ++pt)
                    acc[pt] = __builtin_amdgcn_mfma_f32_32x32x16_bf16(w0, ar[dy+pt], acc[pt], 0,0,0);
            }
        }
    }
}

// head conv GEMM (3ch image, K = tap*4+ci zero-padded to 48), wave's ot half
__device__ __forceinline__ void head_gemm(f16v acc[4], const char* imgb,
                                          const u16* hw, int lane, int ot, int y0) {
    const int r31 = lane & 31, h = lane >> 5;
    #pragma unroll
    for (int kc = 0; kc < 3; ++kc) {
        const s8v w0 = ld_w(hw, kc*1024 + ot*512 + lane*8);
        #pragma unroll
        for (int pt = 0; pt < 4; ++pt) {
            const int y = y0 + pt;
            const int tA = kc*4 + h*2, tB = tA + 1;
            const int pA = (tA <= 8) ? (y + tA/3)*34 + r31 + (tA % 3) : 0;
            const int pB = (tB <= 8) ? (y + tB/3)*34 + r31 + (tB % 3) : 0;
            const uint2 lo = *reinterpret_cast<const uint2*>(imgb + pA*8);
            const uint2 hi = *reinterpret_cast<const uint2*>(imgb + pB*8);
            uint4 tmp; tmp.x = lo.x; tmp.y = lo.y; tmp.z = hi.x; tmp.w = hi.y;
            const s8v bf = __builtin_bit_cast(s8v, tmp);
            acc[pt] = __builtin_amdgcn_mfma_f32_32x32x16_bf16(w0, bf, acc[pt], 0,0,0);
        }
    }
}

// write acc (32 oc half) -> act LDS. C/D: oc_in_32 = i + 8*g + 4*h, col = r31
__device__ __forceinline__ void st_act(char* actb, const f16v acc[4],
                                       int r31, int h, int ot, int y0) {
    #pragma unroll
    for (int pt = 0; pt < 4; ++pt) {
        const int p = (y0 + pt + 1)*34 + r31 + 1;
        #pragma unroll
        for (int g = 0; g < 4; ++g) {
            uint2 wv;
            wv.x = pk2(acc[pt][g*4+0], acc[pt][g*4+1]);
            wv.y = pk2(acc[pt][g*4+2], acc[pt][g*4+3]);
            *reinterpret_cast<uint2*>(actb + SWZB(p, ot*64 + g*16 + h*8)) = wv;
        }
    }
}

// ---------------- SR trunk (MFMA) --------------------------------------------
// 16 waves; wave wv: rows (wv>>1)*4.., oc half (wv&1)*32. One image per block.
__global__ __launch_bounds__(1024, 4) void k_sr(
    const float* __restrict__ inp,
    const float* __restrict__ head_b, const float* __restrict__ body_b,
    const float* __restrict__ tail_b,
    const u16* __restrict__ bw_head, const u16* __restrict__ bw_body,
    const u16* __restrict__ bw_tail,
    const int* __restrict__ perm, const int* __restrict__ vld,
    const int* __restrict__ expert, float* __restrict__ out)
{
    extern __shared__ char lds[];
    char* actb = lds;
    char* imgb = lds + IMG_OFF;
    const int slot = blockIdx.x, t = threadIdx.x;
    const int n = perm[slot];
    float* outp = out + (size_t)n * OUT_PER_IMG;

    if (!vld[slot]) {                      // over-capacity: zeros
        float4 z; z.x = z.y = z.z = z.w = 0.f;
        float4* o4 = (float4*)outp;
        #pragma unroll
        for (int k = 0; k < 3; ++k) o4[k*1024 + t] = z;
        return;
    }
    const int e = expert[n];

    for (int i = t; i < LDS_BYTES/4; i += 1024) ((unsigned*)lds)[i] = 0u;
    __syncthreads();

    const float* src = inp + (size_t)n*3072;
    #pragma unroll
    for (int k = 0; k < 3; ++k) {
        const int i = t + k*1024;
        const int ci = i >> 10, p = i & 1023, y = p >> 5, x = p & 31;
        ((u16*)imgb)[((y+1)*34 + x + 1)*4 + ci] = f2bf(src[i]);
    }
    __syncthreads();

    const int lane = t & 63, wv = t >> 6;
    const int r31 = lane & 31, h = lane >> 5;
    const int ot = wv & 1;                 // oc half
    const int y0 = (wv >> 1) * 4;          // wave's 4 output rows

    const u16* hw = bw_head + e*3072;
    const float* hb = head_b + e*64 + ot*32;

    f16v acc[4];

    // ---- head
    bias_init(acc, hb, h);
    head_gemm(acc, imgb, hw, lane, ot, y0);
    st_act(actb, acc, r31, h, ot, y0);
    __syncthreads();

    // ---- body blocks
    for (int b = 0; b < NBLK; ++b) {
        const u16* wb = bw_body + (size_t)(e*NBLK + b)*36864;
        bias_init(acc, body_b + (e*NBLK + b)*64 + ot*32, h);
        body_gemm(acc, actb, wb, lane, ot, y0);
        #pragma unroll
        for (int pt = 0; pt < 4; ++pt)
            #pragma unroll
            for (int i = 0; i < 16; ++i)
                acc[pt][i] = fmaxf(acc[pt][i], 0.f);
        if (b == NBLK-1) {                  // + h0 recomputed from staged image
            bias_add(acc, hb, h);
            head_gemm(acc, imgb, hw, lane, ot, y0);
        }
        __syncthreads();
        st_act(actb, acc, r31, h, ot, y0);
        __syncthreads();
    }

    // ---- tail: conv 64->12 via 16x16x32 MFMA (oc padded 12->16) + pixel shuffle
    // wave = 2 rows x 32 px = 4 tiles of 16 px. A row=lane&15 (oc), k=(lane>>4)*8+j.
    {
        const u16* tw = bw_tail + e*9216;
        const float* tb = tail_b + e*12;
        const int y0t = wv * 2;
        const int g16 = lane >> 4;          // 0..3: oc group (A k-half selector too)
        const int p16 = lane & 15;
        f4v tacc[4];
        #pragma unroll
        for (int tl = 0; tl < 4; ++tl)
            #pragma unroll
            for (int i = 0; i < 4; ++i) {
                const int oc = g16*4 + i;
                tacc[tl][i] = (oc < 12) ? tb[oc] : 0.f;
            }
        #pragma unroll
        for (int ks = 0; ks < 18; ++ks) {
            const int tap = ks >> 1, half = ks & 1;
            const int dy = tap / 3, dx = tap % 3;
            const s8v twf = ld_w(tw, ks*512 + lane*8);
            const int cb = half*64 + g16*16;     // ci = half*32 + g16*8 (+j), bytes x2
            #pragma unroll
            for (int tl = 0; tl < 4; ++tl) {
                const int row = y0t + (tl >> 1);
                const int p = (row + dy)*34 + (tl & 1)*16 + p16 + dx;
                const s8v bfr = ld_act(actb, p, cb);
                tacc[tl] = __builtin_amdgcn_mfma_f32_16x16x32_bf16(twf, bfr, tacc[tl], 0,0,0);
            }
        }
        // store: C col=lane&15=px, row=(lane>>4)*4+reg=oc. oc<12 <=> g16<3.
        if (g16 < 3) {
            #pragma unroll
            for (int tl = 0; tl < 4; ++tl) {
                const int ys = y0t + (tl >> 1);
                const int xo = 2*((tl & 1)*16 + p16);
                float2 v01, v23;
                v01.x = tacc[tl][0]; v01.y = tacc[tl][1];
                v23.x = tacc[tl][2]; v23.y = tacc[tl][3];
                *reinterpret_cast<float2*>(&outp[g16*4096 + (2*ys)*64 + xo])     = v01;
                *reinterpret_cast<float2*>(&outp[g16*4096 + (2*ys + 1)*64 + xo]) = v23;
            }
        }
    }
}

extern "C" void kernel_launch(void* const* d_in, const int* in_sizes, int n_in,
                              void* d_out, int out_size, void* d_ws, size_t ws_size,
                              hipStream_t stream) {
    const float* inp     = (const float*)d_in[0];
    const float* cls_w1  = (const float*)d_in[1];
    const float* cls_b1  = (const float*)d_in[2];
    const float* cls_wfc = (const float*)d_in[3];
    const float* cls_bfc = (const float*)d_in[4];
    const float* head_w  = (const float*)d_in[5];
    const float* head_b  = (const float*)d_in[6];
    const float* body_w  = (const float*)d_in[7];
    const float* body_b  = (const float*)d_in[8];
    const float* tail_w  = (const float*)d_in[9];
    const float* tail_b  = (const float*)d_in[10];
    float* out = (float*)d_out;

    char* ws = (char*)d_ws;
    int* expert = (int*)(ws + WS_EXPERT);
    int* perm   = (int*)(ws + WS_PERM);
    int* vld    = (int*)(ws + WS_VLD);
    u16* bw_body = (u16*)(ws + WS_BODY);
    u16* bw_head = (u16*)(ws + WS_HEAD);
    u16* bw_tail = (u16*)(ws + WS_TAIL);

    hipFuncSetAttribute((const void*)k_sr,
                        hipFuncAttributeMaxDynamicSharedMemorySize, LDS_BYTES);

    k_prep<<<(638976 + 255)/256, 256, 0, stream>>>(head_w, body_w, tail_w,
                                                   bw_head, bw_body, bw_tail);
    k_classify<<<N_IMG, 256, 0, stream>>>(inp, cls_w1, cls_b1, cls_wfc, cls_bfc, expert);
    k_route<<<1, 256, 0, stream>>>(expert, perm, vld);
    k_sr<<<N_IMG, 1024, LDS_BYTES, stream>>>(inp, head_b, body_b, tail_b,
                                             bw_head, bw_body, bw_tail,
                                             perm, vld, expert, out);
}